// Round 9
// baseline (188.654 us; speedup 1.0000x reference)
//
#include <hip/hip_runtime.h>

#define NN 4096
#define DD 512
#define EE 64
#define HH 8

typedef _Float16 f16;
typedef f16 f16x4 __attribute__((ext_vector_type(4)));
typedef f16 f16x8 __attribute__((ext_vector_type(8)));
typedef float f32x4 __attribute__((ext_vector_type(4)));

// hardware exp2 (v_exp_f32). NOTE: __exp2f collides with glibc math.h macros.
__device__ __forceinline__ float hexp2(float x) { return __builtin_amdgcn_exp2f(x); }

// ---------------- fused prep: converts + weight transposes, 1 launch ----------------
__device__ void tile_transpose_cvt(const float* __restrict__ src, f16* __restrict__ dst,
                                   int R, int C, int bx, int by, int tid)
{
    __shared__ float t[32][33];
    const int tx = tid & 31, ty = tid >> 5;
    #pragma unroll
    for (int i = 0; i < 4; ++i) {
        int r = ty + i * 8;
        t[r][tx] = src[(size_t)(by + r) * C + bx + tx];
    }
    __syncthreads();
    #pragma unroll
    for (int i = 0; i < 4; ++i) {
        int c = ty + i * 8;
        dst[(size_t)(bx + c) * R + by + tx] = (f16)t[tx][c];
    }
}

// grid (256, 6): y=0 x->f16 (8 passes), y=1 ffn_w->f16, y=2..4 wq/wk/wv transpose, y=5 w_mh transpose
__global__ __launch_bounds__(256) void prep_kernel(
    const float* __restrict__ x, const float* __restrict__ ffn_w,
    const float* __restrict__ wq, const float* __restrict__ wk, const float* __restrict__ wv,
    const float* __restrict__ w_mh,
    f16* __restrict__ xh, f16* __restrict__ ffnT, f16* __restrict__ wqkvT, f16* __restrict__ wmhT)
{
    const int job = blockIdx.y;
    const int tid = threadIdx.x;
    if (job == 0) {
        size_t i = ((size_t)blockIdx.x * 256 + tid) * 4;
        const size_t step = (size_t)256 * 256 * 4;
        for (; i < (size_t)NN * DD; i += step) {
            float4 t = *(const float4*)(x + i);
            f16x4 h = { (f16)t.x, (f16)t.y, (f16)t.z, (f16)t.w };
            *(f16x4*)(xh + i) = h;
        }
    } else if (job == 1) {
        size_t i = ((size_t)blockIdx.x * 256 + tid) * 4;   // DD*DD = 256 blocks exactly
        float4 t = *(const float4*)(ffn_w + i);
        f16x4 h = { (f16)t.x, (f16)t.y, (f16)t.z, (f16)t.w };
        *(f16x4*)(ffnT + i) = h;
    } else if (job <= 4) {
        const float* src = (job == 2) ? wq : (job == 3) ? wk : wv;
        f16* dst = wqkvT + (size_t)(job - 2) * HH * EE * DD;
        const int z = blockIdx.x >> 5;        // head 0..7
        const int tile = blockIdx.x & 31;     // 2 (E) x 16 (D)
        tile_transpose_cvt(src + (size_t)z * DD * EE, dst + (size_t)z * DD * EE,
                           DD, EE, (tile & 1) * 32, (tile >> 1) * 32, tid);
    } else {
        const int tile = blockIdx.x;          // 16 x 16
        tile_transpose_cvt(w_mh, wmhT, DD, DD, (tile & 15) * 32, (tile >> 4) * 32, tid);
    }
}

// ---------------- QKV GEMM via MFMA: C[64n x 64col] tiles, K=512, reg-prefetched ----------------
__global__ __launch_bounds__(256) void qkv_mfma_kernel(
    const f16* __restrict__ A, const f16* __restrict__ BT,
    f16* __restrict__ qh, f16* __restrict__ kh, f16* __restrict__ vTh)
{
    __shared__ f16 As[64][72];
    __shared__ f16 Bs[64][72];
    const int tid = threadIdx.x;
    const int n0 = blockIdx.x * 64;
    const int cb = blockIdx.y;
    const int sel = cb >> 3, h = cb & 7;
    const f16* Arow = A + (size_t)n0 * DD;
    const f16* Brow = BT + (size_t)cb * 64 * DD;

    const int lane = tid & 63, wave = tid >> 6;
    const int l16 = lane & 15, quad = lane >> 4;
    const int m0 = wave * 16;

    const int r1 = tid >> 3, c1 = (tid & 7) * 8;
    const int r2 = (tid + 256) >> 3, c2 = ((tid + 256) & 7) * 8;

    f32x4 acc[4];
    #pragma unroll
    for (int t = 0; t < 4; ++t) acc[t] = (f32x4){0.f, 0.f, 0.f, 0.f};

    // register prefetch of first chunk
    f16x8 a1 = *(const f16x8*)(Arow + (size_t)r1 * DD + c1);
    f16x8 a2 = *(const f16x8*)(Arow + (size_t)r2 * DD + c2);
    f16x8 b1 = *(const f16x8*)(Brow + (size_t)r1 * DD + c1);
    f16x8 b2 = *(const f16x8*)(Brow + (size_t)r2 * DD + c2);

    for (int kt = 0; kt < DD; kt += 64) {
        __syncthreads();
        *(f16x8*)(&As[r1][c1]) = a1;
        *(f16x8*)(&As[r2][c2]) = a2;
        *(f16x8*)(&Bs[r1][c1]) = b1;
        *(f16x8*)(&Bs[r2][c2]) = b2;
        __syncthreads();
        if (kt + 64 < DD) {
            a1 = *(const f16x8*)(Arow + (size_t)r1 * DD + kt + 64 + c1);
            a2 = *(const f16x8*)(Arow + (size_t)r2 * DD + kt + 64 + c2);
            b1 = *(const f16x8*)(Brow + (size_t)r1 * DD + kt + 64 + c1);
            b2 = *(const f16x8*)(Brow + (size_t)r2 * DD + kt + 64 + c2);
        }
        #pragma unroll
        for (int kk = 0; kk < 64; kk += 32) {
            f16x8 a = *(const f16x8*)(&As[m0 + l16][kk + quad * 8]);
            #pragma unroll
            for (int t = 0; t < 4; ++t) {
                f16x8 b = *(const f16x8*)(&Bs[t * 16 + l16][kk + quad * 8]);
                acc[t] = __builtin_amdgcn_mfma_f32_16x16x32_f16(a, b, acc[t], 0, 0, 0);
            }
        }
    }

    if (sel == 2) {
        #pragma unroll
        for (int t = 0; t < 4; ++t) {
            int e = t * 16 + l16;
            f16x4 v = { (f16)acc[t][0], (f16)acc[t][1], (f16)acc[t][2], (f16)acc[t][3] };
            *(f16x4*)(vTh + ((size_t)h * EE + e) * NN + n0 + m0 + quad * 4) = v;
        }
    } else {
        f16* o = (sel == 0) ? qh : kh;
        // q: bake 1/sqrt(E) * log2(e) so attention can use raw v_exp_f32 (exp2)
        const float s = (sel == 0) ? 0.125f * 1.44269504088896f : 1.0f;
        #pragma unroll
        for (int r = 0; r < 4; ++r) {
            int row = n0 + m0 + quad * 4 + r;
            #pragma unroll
            for (int t = 0; t < 4; ++t)
                o[(size_t)h * NN * EE + (size_t)row * EE + t * 16 + l16] = (f16)(acc[t][r] * s);
        }
    }
}

// ---------------- Flash attention v6: r8 structure + f16 normalized partials ----------------
// 16x16 MFMA, key bit-swizzle (reg-only P), BQ=128 (2 q-strips/wave, K/V frag reuse x2).
// Partials stored per-split normalized: Ohat_s = O_s / l_s (f16-safe magnitudes);
// combine does z = sum_s (l_s/sum l) * Ohat_s.
#define BQ 128
#define BK 64
#define LK (BK + 12)   // 76 halfs: frag-read row bank-step 6 mod 32 -> conflict-free

__global__ __launch_bounds__(256) void attn_mfma_kernel(
    const f16* __restrict__ q, const f16* __restrict__ k,
    const f16* __restrict__ vT, f16* __restrict__ Opart, float* __restrict__ lpart)
{
    __shared__ f16 Ks[BK][LK];    // permuted key rows
    __shared__ f16 VsT[EE][LK];   // [e][key]

    const int tid = threadIdx.x;
    const int h = blockIdx.y;
    const int n0 = blockIdx.x * BQ;
    const int sp = blockIdx.z;
    const int nsp = gridDim.z;
    const int wave = tid >> 6;
    const int lane = tid & 63;
    const int l16 = lane & 15;
    const int quad = lane >> 4;
    const int m0 = wave * 16;

    const f16* qh = q + (size_t)h * NN * EE;
    const f16* kh = k + (size_t)h * NN * EE;
    const f16* vh = vT + (size_t)h * NN * EE;  // [e][n]

    // Q B-fragments for both strips (loaded once from global)
    f16x8 qf[2][2];
    #pragma unroll
    for (int s = 0; s < 2; ++s) {
        const f16* qb = qh + (size_t)(n0 + s * 64 + m0 + l16) * EE;
        qf[s][0] = *(const f16x8*)(qb + quad * 8);
        qf[s][1] = *(const f16x8*)(qb + 32 + quad * 8);
    }

    float lp[2] = {0.f, 0.f};
    f32x4 O[2][4];
    #pragma unroll
    for (int s = 0; s < 2; ++s)
        #pragma unroll
        for (int t = 0; t < 4; ++t) O[s][t] = (f32x4){0.f, 0.f, 0.f, 0.f};

    const int span = NN / nsp;
    const int k_begin = sp * span;
    const int k_end = k_begin + span;

    const int srow = tid >> 3, sc8 = (tid & 7) * 8;
    const int srow2 = (tid + 256) >> 3, sc82 = ((tid + 256) & 7) * 8;
    // key -> permuted LDS row: bits T,q,u,c -> T,u,q,c (verified r6)
    #define KPERM(kk_) (((kk_) & 0x23) | (((kk_) & 0x04) << 2) | (((kk_) & 0x18) >> 1))
    const int prow1 = KPERM(srow), prow2 = KPERM(srow2);

    // register prefetch of first tile
    f16x8 kr0 = *(const f16x8*)(kh + (size_t)(k_begin + srow) * EE + sc8);
    f16x8 kr1 = *(const f16x8*)(kh + (size_t)(k_begin + srow2) * EE + sc82);
    f16x8 vr0 = *(const f16x8*)(vh + (size_t)srow * NN + k_begin + sc8);
    f16x8 vr1 = *(const f16x8*)(vh + (size_t)srow2 * NN + k_begin + sc82);

    for (int kt = k_begin; kt < k_end; kt += BK) {
        __syncthreads();
        *(f16x8*)(&Ks[prow1][sc8]) = kr0;
        *(f16x8*)(&Ks[prow2][sc82]) = kr1;
        *(f16x8*)(&VsT[srow][sc8]) = vr0;
        *(f16x8*)(&VsT[srow2][sc82]) = vr1;
        __syncthreads();

        if (kt + BK < k_end) {   // prefetch next tile
            kr0 = *(const f16x8*)(kh + (size_t)(kt + BK + srow) * EE + sc8);
            kr1 = *(const f16x8*)(kh + (size_t)(kt + BK + srow2) * EE + sc82);
            vr0 = *(const f16x8*)(vh + (size_t)srow * NN + kt + BK + sc8);
            vr1 = *(const f16x8*)(vh + (size_t)srow2 * NN + kt + BK + sc82);
        }

        // S^T = K.Q^T per key-tile; each K-frag read feeds both q-strips
        f16x8 bf[2][2];
        #pragma unroll
        for (int t = 0; t < 4; ++t) {
            f16x8 a0 = *(const f16x8*)(&Ks[t * 16 + l16][quad * 8]);
            f16x8 a1 = *(const f16x8*)(&Ks[t * 16 + l16][32 + quad * 8]);
            #pragma unroll
            for (int s = 0; s < 2; ++s) {
                f32x4 st = {0.f, 0.f, 0.f, 0.f};
                st = __builtin_amdgcn_mfma_f32_16x16x32_f16(a0, qf[s][0], st, 0, 0, 0);
                st = __builtin_amdgcn_mfma_f32_16x16x32_f16(a1, qf[s][1], st, 0, 0, 0);
                float p0 = hexp2(st[0]);
                float p1 = hexp2(st[1]);
                float p2 = hexp2(st[2]);
                float p3 = hexp2(st[3]);
                lp[s] += (p0 + p1) + (p2 + p3);
                f16x8& b = bf[s][t >> 1];
                const int o = (t & 1) * 4;
                b[o + 0] = (f16)p0; b[o + 1] = (f16)p1;
                b[o + 2] = (f16)p2; b[o + 3] = (f16)p3;
            }
        }

        // O^T += V^T P^T ; each V-frag read feeds both strips
        #pragma unroll
        for (int te = 0; te < 4; ++te) {
            f16x8 v0 = *(const f16x8*)(&VsT[te * 16 + l16][quad * 8]);
            f16x8 v1 = *(const f16x8*)(&VsT[te * 16 + l16][32 + quad * 8]);
            #pragma unroll
            for (int s = 0; s < 2; ++s) {
                O[s][te] = __builtin_amdgcn_mfma_f32_16x16x32_f16(v0, bf[s][0], O[s][te], 0, 0, 0);
                O[s][te] = __builtin_amdgcn_mfma_f32_16x16x32_f16(v1, bf[s][1], O[s][te], 0, 0, 0);
            }
        }
    }

    // epilogue per strip: normalize by local l, store f16
    #pragma unroll
    for (int s = 0; s < 2; ++s) {
        float l = lp[s];
        l += __shfl_xor(l, 16);
        l += __shfl_xor(l, 32);
        const int row = n0 + s * 64 + m0 + l16;
        if (quad == 0)
            lpart[(size_t)sp * HH * NN + (size_t)h * NN + row] = l;
        const float inv = 1.f / l;
        f16* obase = Opart + ((size_t)sp * NN + row) * DD + h * EE;
        #pragma unroll
        for (int te = 0; te < 4; ++te) {
            f16x4 v = { (f16)(O[s][te][0] * inv), (f16)(O[s][te][1] * inv),
                        (f16)(O[s][te][2] * inv), (f16)(O[s][te][3] * inv) };
            *(f16x4*)(obase + te * 16 + quad * 4) = v;
        }
    }
}

// ---------------- combine: zh = sum_s (l_s/sum l) * Ohat_s, f16 out ----------------
__global__ __launch_bounds__(256) void attn_combine_kernel(
    const f16* __restrict__ Opart, const float* __restrict__ lpart, f16* __restrict__ zh, int nsp)
{
    const size_t idx = ((size_t)blockIdx.x * 256 + threadIdx.x) * 8;
    const int n = (int)(idx >> 9);
    const int h = (int)((idx & 511) >> 6);
    float lw[8];
    float lsum = 0.f;
    for (int s = 0; s < nsp; ++s) {
        lw[s] = lpart[(size_t)s * HH * NN + (size_t)h * NN + n];
        lsum += lw[s];
    }
    const float inv = 1.f / lsum;
    float acc[8];
    #pragma unroll
    for (int i = 0; i < 8; ++i) acc[i] = 0.f;
    for (int s = 0; s < nsp; ++s) {
        f16x8 o = *(const f16x8*)(Opart + (size_t)s * NN * DD + idx);
        const float w = lw[s] * inv;
        #pragma unroll
        for (int i = 0; i < 8; ++i) acc[i] += w * (float)o[i];
    }
    f16x8 z;
    #pragma unroll
    for (int i = 0; i < 8; ++i) z[i] = (f16)acc[i];
    *(f16x8*)(zh + idx) = z;
}

// ---------------- GEMM via MFMA + bias/residual epilogue, fp32 out, reg-prefetched ----------------
__global__ __launch_bounds__(256) void gemm_mfma_kernel(
    const f16* __restrict__ A, const f16* __restrict__ BT,
    const float* __restrict__ bias, const float* __restrict__ resid32,
    const f16* __restrict__ resid16, float* __restrict__ out)
{
    __shared__ f16 As[64][72];
    __shared__ f16 Bs[64][72];
    const int tid = threadIdx.x;
    const int n0 = blockIdx.x * 64;
    const int j0 = blockIdx.y * 64;
    const f16* Arow = A + (size_t)n0 * DD;
    const f16* Brow = BT + (size_t)j0 * DD;

    const int lane = tid & 63, wave = tid >> 6;
    const int l16 = lane & 15, quad = lane >> 4;
    const int m0 = wave * 16;

    const int r1 = tid >> 3, c1 = (tid & 7) * 8;
    const int r2 = (tid + 256) >> 3, c2 = ((tid + 256) & 7) * 8;

    f32x4 acc[4];
    #pragma unroll
    for (int t = 0; t < 4; ++t) acc[t] = (f32x4){0.f, 0.f, 0.f, 0.f};

    f16x8 a1 = *(const f16x8*)(Arow + (size_t)r1 * DD + c1);
    f16x8 a2 = *(const f16x8*)(Arow + (size_t)r2 * DD + c2);
    f16x8 b1 = *(const f16x8*)(Brow + (size_t)r1 * DD + c1);
    f16x8 b2 = *(const f16x8*)(Brow + (size_t)r2 * DD + c2);

    for (int kt = 0; kt < DD; kt += 64) {
        __syncthreads();
        *(f16x8*)(&As[r1][c1]) = a1;
        *(f16x8*)(&As[r2][c2]) = a2;
        *(f16x8*)(&Bs[r1][c1]) = b1;
        *(f16x8*)(&Bs[r2][c2]) = b2;
        __syncthreads();
        if (kt + 64 < DD) {
            a1 = *(const f16x8*)(Arow + (size_t)r1 * DD + kt + 64 + c1);
            a2 = *(const f16x8*)(Arow + (size_t)r2 * DD + kt + 64 + c2);
            b1 = *(const f16x8*)(Brow + (size_t)r1 * DD + kt + 64 + c1);
            b2 = *(const f16x8*)(Brow + (size_t)r2 * DD + kt + 64 + c2);
        }
        #pragma unroll
        for (int kk = 0; kk < 64; kk += 32) {
            f16x8 a = *(const f16x8*)(&As[m0 + l16][kk + quad * 8]);
            #pragma unroll
            for (int t = 0; t < 4; ++t) {
                f16x8 b = *(const f16x8*)(&Bs[t * 16 + l16][kk + quad * 8]);
                acc[t] = __builtin_amdgcn_mfma_f32_16x16x32_f16(a, b, acc[t], 0, 0, 0);
            }
        }
    }

    #pragma unroll
    for (int r = 0; r < 4; ++r) {
        int row = n0 + m0 + quad * 4 + r;
        #pragma unroll
        for (int t = 0; t < 4; ++t) {
            int col = j0 + t * 16 + l16;
            float v = acc[t][r];
            if (bias)    v += bias[col];
            if (resid32) v += resid32[(size_t)row * DD + col];
            if (resid16) v += (float)resid16[(size_t)row * DD + col];
            out[(size_t)row * DD + col] = v;
        }
    }
}

// ---------------- row LayerNorm: y fp32 [N][512] -> f16 and/or fp32 out ----------------
__global__ __launch_bounds__(256) void ln_kernel(
    const float* __restrict__ y, const float* __restrict__ g, const float* __restrict__ b,
    f16* __restrict__ oh, float* __restrict__ of)
{
    const int lane = threadIdx.x & 63, wave = threadIdx.x >> 6;
    const int row = blockIdx.x * 4 + wave;
    const float* yr = y + (size_t)row * DD;
    f32x4 v0 = *(const f32x4*)(yr + lane * 4);
    f32x4 v1 = *(const f32x4*)(yr + 256 + lane * 4);
    float s = (v0[0] + v0[1]) + (v0[2] + v0[3]) + (v1[0] + v1[1]) + (v1[2] + v1[3]);
    float q = (v0[0]*v0[0] + v0[1]*v0[1]) + (v0[2]*v0[2] + v0[3]*v0[3])
            + (v1[0]*v1[0] + v1[1]*v1[1]) + (v1[2]*v1[2] + v1[3]*v1[3]);
    #pragma unroll
    for (int o = 1; o < 64; o <<= 1) { s += __shfl_xor(s, o); q += __shfl_xor(q, o); }
    float mean = s * (1.f / DD);
    float var = q * (1.f / DD) - mean * mean;
    float inv = rsqrtf(var + 1e-5f);

    f32x4 g0 = *(const f32x4*)(g + lane * 4);
    f32x4 g1 = *(const f32x4*)(g + 256 + lane * 4);
    f32x4 b0 = *(const f32x4*)(b + lane * 4);
    f32x4 b1 = *(const f32x4*)(b + 256 + lane * 4);
    f32x4 o0, o1;
    #pragma unroll
    for (int i = 0; i < 4; ++i) {
        o0[i] = (v0[i] - mean) * inv * g0[i] + b0[i];
        o1[i] = (v1[i] - mean) * inv * g1[i] + b1[i];
    }
    if (oh) {
        f16x4 h0 = { (f16)o0[0], (f16)o0[1], (f16)o0[2], (f16)o0[3] };
        f16x4 h1 = { (f16)o1[0], (f16)o1[1], (f16)o1[2], (f16)o1[3] };
        *(f16x4*)(oh + (size_t)row * DD + lane * 4) = h0;
        *(f16x4*)(oh + (size_t)row * DD + 256 + lane * 4) = h1;
    }
    if (of) {
        *(f32x4*)(of + (size_t)row * DD + lane * 4) = o0;
        *(f32x4*)(of + (size_t)row * DD + 256 + lane * 4) = o1;
    }
}

extern "C" void kernel_launch(void* const* d_in, const int* in_sizes, int n_in,
                              void* d_out, int out_size, void* d_ws, size_t ws_size,
                              hipStream_t stream) {
    const float* x     = (const float*)d_in[0];
    const float* wq    = (const float*)d_in[1];
    const float* wk    = (const float*)d_in[2];
    const float* wv    = (const float*)d_in[3];
    const float* w_mh  = (const float*)d_in[4];
    const float* ln1_g = (const float*)d_in[5];
    const float* ln1_b = (const float*)d_in[6];
    const float* ffn_w = (const float*)d_in[7];
    const float* ffn_b = (const float*)d_in[8];
    const float* ln2_g = (const float*)d_in[9];
    const float* ln2_b = (const float*)d_in[10];
    float* out = (float*)d_out;

    // pool of f16 buffers that live across phases
    const size_t poolBytes = ((size_t)3 * HH * EE * DD + 2 * (size_t)DD * DD
                            + 3 * (size_t)HH * NN * EE + 2 * (size_t)NN * DD) * 2;
    // K-split count by available workspace (deterministic per session).
    // Opart is f16 now: regionA(SP) = SP*NN*DD*2 + SP*HH*NN*4 bytes.
    int SP = 2;
    {
        size_t need8 = (size_t)8 * NN * DD * 2 + (size_t)8 * HH * NN * 4 + poolBytes + 4096;
        size_t need4 = (size_t)4 * NN * DD * 2 + (size_t)4 * HH * NN * 4 + poolBytes + 4096;
        if (ws_size >= need8) SP = 8; else if (ws_size >= need4) SP = 4;
    }

    // region A (aliased): xh (pre-attn) / Opart+lpart (attn..combine) / y (post-combine)
    char* base = (char*)d_ws;
    f16* Opart = (f16*)base;                                        // SP*NN*DD f16
    float* lpart = (float*)(base + (size_t)SP * NN * DD * 2);       // SP*HH*NN f32
    f16* xh   = (f16*)base;                                         // alias (pre-attention)
    float* y  = (float*)base;                                       // alias (post-combine)
    size_t regionA = (size_t)SP * NN * DD * 2 + (size_t)SP * HH * NN * 4;
    regionA = (regionA + 255) & ~(size_t)255;
    f16* p = (f16*)(base + regionA);
    f16* wqkvT  = p; p += (size_t)3 * HH * EE * DD;           // [sel][h][e][d]
    f16* wmhT   = p; p += (size_t)DD * DD;                    // [j][k]
    f16* ffnT   = p; p += (size_t)DD * DD;                    // [j][k]
    f16* qh     = p; p += (size_t)HH * NN * EE;               // [h][n][e], scale baked
    f16* kh     = p; p += (size_t)HH * NN * EE;               // [h][n][e]
    f16* vTh    = p; p += (size_t)HH * NN * EE;               // [h][e][n]
    f16* zh     = p; p += (size_t)NN * DD;                    // [n][h*e]
    f16* nzh    = p; p += (size_t)NN * DD;                    // LN1 out

    // prep (single launch)
    prep_kernel<<<dim3(256, 6), 256, 0, stream>>>(x, ffn_w, wq, wk, wv, w_mh,
                                                  xh, ffnT, wqkvT, wmhT);

    // main chain
    qkv_mfma_kernel<<<dim3(NN / 64, 24), 256, 0, stream>>>(xh, wqkvT, qh, kh, vTh);
    attn_mfma_kernel<<<dim3(NN / BQ, HH, SP), 256, 0, stream>>>(qh, kh, vTh, Opart, lpart);
    attn_combine_kernel<<<dim3(NN * DD / 2048), 256, 0, stream>>>(Opart, lpart, zh, SP);
    gemm_mfma_kernel<<<dim3(NN / 64, DD / 64), 256, 0, stream>>>(zh, wmhT, nullptr, x, nullptr, y);
    ln_kernel<<<dim3(NN / 4), 256, 0, stream>>>(y, ln1_g, ln1_b, nzh, nullptr);
    gemm_mfma_kernel<<<dim3(NN / 64, DD / 64), 256, 0, stream>>>(nzh, ffnT, ffn_b, nullptr, nzh, y);
    ln_kernel<<<dim3(NN / 4), 256, 0, stream>>>(y, ln2_g, ln2_b, nullptr, out);
}

// Round 10
// 179.553 us; speedup vs baseline: 1.0507x; 1.0507x over previous
//
#include <hip/hip_runtime.h>

#define NN 4096
#define DD 512
#define EE 64
#define HH 8

typedef _Float16 f16;
typedef f16 f16x4 __attribute__((ext_vector_type(4)));
typedef f16 f16x8 __attribute__((ext_vector_type(8)));
typedef float f32x4 __attribute__((ext_vector_type(4)));

// hardware exp2 (v_exp_f32). NOTE: __exp2f collides with glibc math.h macros.
__device__ __forceinline__ float hexp2(float x) { return __builtin_amdgcn_exp2f(x); }

// ---------------- fused prep: converts + weight transposes, 1 launch ----------------
__device__ void tile_transpose_cvt(const float* __restrict__ src, f16* __restrict__ dst,
                                   int R, int C, int bx, int by, int tid)
{
    __shared__ float t[32][33];
    const int tx = tid & 31, ty = tid >> 5;
    #pragma unroll
    for (int i = 0; i < 4; ++i) {
        int r = ty + i * 8;
        t[r][tx] = src[(size_t)(by + r) * C + bx + tx];
    }
    __syncthreads();
    #pragma unroll
    for (int i = 0; i < 4; ++i) {
        int c = ty + i * 8;
        dst[(size_t)(bx + c) * R + by + tx] = (f16)t[tx][c];
    }
}

// grid (256, 6): y=0 x->f16 (8 passes), y=1 ffn_w->f16, y=2..4 wq/wk/wv transpose, y=5 w_mh transpose
__global__ __launch_bounds__(256) void prep_kernel(
    const float* __restrict__ x, const float* __restrict__ ffn_w,
    const float* __restrict__ wq, const float* __restrict__ wk, const float* __restrict__ wv,
    const float* __restrict__ w_mh,
    f16* __restrict__ xh, f16* __restrict__ ffnT, f16* __restrict__ wqkvT, f16* __restrict__ wmhT)
{
    const int job = blockIdx.y;
    const int tid = threadIdx.x;
    if (job == 0) {
        size_t i = ((size_t)blockIdx.x * 256 + tid) * 4;
        const size_t step = (size_t)256 * 256 * 4;
        for (; i < (size_t)NN * DD; i += step) {
            float4 t = *(const float4*)(x + i);
            f16x4 h = { (f16)t.x, (f16)t.y, (f16)t.z, (f16)t.w };
            *(f16x4*)(xh + i) = h;
        }
    } else if (job == 1) {
        size_t i = ((size_t)blockIdx.x * 256 + tid) * 4;   // DD*DD = 256 blocks exactly
        float4 t = *(const float4*)(ffn_w + i);
        f16x4 h = { (f16)t.x, (f16)t.y, (f16)t.z, (f16)t.w };
        *(f16x4*)(ffnT + i) = h;
    } else if (job <= 4) {
        const float* src = (job == 2) ? wq : (job == 3) ? wk : wv;
        f16* dst = wqkvT + (size_t)(job - 2) * HH * EE * DD;
        const int z = blockIdx.x >> 5;        // head 0..7
        const int tile = blockIdx.x & 31;     // 2 (E) x 16 (D)
        tile_transpose_cvt(src + (size_t)z * DD * EE, dst + (size_t)z * DD * EE,
                           DD, EE, (tile & 1) * 32, (tile >> 1) * 32, tid);
    } else {
        const int tile = blockIdx.x;          // 16 x 16
        tile_transpose_cvt(w_mh, wmhT, DD, DD, (tile & 15) * 32, (tile >> 4) * 32, tid);
    }
}

// ---------------- QKV GEMM via MFMA: C[64n x 64col], K=512, LDS double-buffered ----------------
__global__ __launch_bounds__(256) void qkv_mfma_kernel(
    const f16* __restrict__ A, const f16* __restrict__ BT,
    f16* __restrict__ qh, f16* __restrict__ kh, f16* __restrict__ vTh)
{
    __shared__ f16 As[2][64][72];
    __shared__ f16 Bs[2][64][72];
    const int tid = threadIdx.x;
    const int n0 = blockIdx.x * 64;
    const int cb = blockIdx.y;
    const int sel = cb >> 3, h = cb & 7;
    const f16* Arow = A + (size_t)n0 * DD;
    const f16* Brow = BT + (size_t)cb * 64 * DD;

    const int lane = tid & 63, wave = tid >> 6;
    const int l16 = lane & 15, quad = lane >> 4;
    const int m0 = wave * 16;

    const int r1 = tid >> 3, c1 = (tid & 7) * 8;
    const int r2 = (tid + 256) >> 3, c2 = ((tid + 256) & 7) * 8;

    f32x4 acc[4];
    #pragma unroll
    for (int t = 0; t < 4; ++t) acc[t] = (f32x4){0.f, 0.f, 0.f, 0.f};

    f16x8 a1 = *(const f16x8*)(Arow + (size_t)r1 * DD + c1);
    f16x8 a2 = *(const f16x8*)(Arow + (size_t)r2 * DD + c2);
    f16x8 b1 = *(const f16x8*)(Brow + (size_t)r1 * DD + c1);
    f16x8 b2 = *(const f16x8*)(Brow + (size_t)r2 * DD + c2);

    int buf = 0;
    for (int kt = 0; kt < DD; kt += 64) {
        *(f16x8*)(&As[buf][r1][c1]) = a1;
        *(f16x8*)(&As[buf][r2][c2]) = a2;
        *(f16x8*)(&Bs[buf][r1][c1]) = b1;
        *(f16x8*)(&Bs[buf][r2][c2]) = b2;
        __syncthreads();   // single barrier: writes to buf visible; other buffer untouched
        if (kt + 64 < DD) {
            a1 = *(const f16x8*)(Arow + (size_t)r1 * DD + kt + 64 + c1);
            a2 = *(const f16x8*)(Arow + (size_t)r2 * DD + kt + 64 + c2);
            b1 = *(const f16x8*)(Brow + (size_t)r1 * DD + kt + 64 + c1);
            b2 = *(const f16x8*)(Brow + (size_t)r2 * DD + kt + 64 + c2);
        }
        #pragma unroll
        for (int kk = 0; kk < 64; kk += 32) {
            f16x8 a = *(const f16x8*)(&As[buf][m0 + l16][kk + quad * 8]);
            #pragma unroll
            for (int t = 0; t < 4; ++t) {
                f16x8 b = *(const f16x8*)(&Bs[buf][t * 16 + l16][kk + quad * 8]);
                acc[t] = __builtin_amdgcn_mfma_f32_16x16x32_f16(a, b, acc[t], 0, 0, 0);
            }
        }
        buf ^= 1;
    }

    if (sel == 2) {
        #pragma unroll
        for (int t = 0; t < 4; ++t) {
            int e = t * 16 + l16;
            f16x4 v = { (f16)acc[t][0], (f16)acc[t][1], (f16)acc[t][2], (f16)acc[t][3] };
            *(f16x4*)(vTh + ((size_t)h * EE + e) * NN + n0 + m0 + quad * 4) = v;
        }
    } else {
        f16* o = (sel == 0) ? qh : kh;
        // q: bake 1/sqrt(E) * log2(e) so attention can use raw v_exp_f32 (exp2)
        const float s = (sel == 0) ? 0.125f * 1.44269504088896f : 1.0f;
        #pragma unroll
        for (int r = 0; r < 4; ++r) {
            int row = n0 + m0 + quad * 4 + r;
            #pragma unroll
            for (int t = 0; t < 4; ++t)
                o[(size_t)h * NN * EE + (size_t)row * EE + t * 16 + l16] = (f16)(acc[t][r] * s);
        }
    }
}

// ---------------- Flash attention v7: r9 structure + LDS double-buffer (1 barrier/iter) ----------------
#define BQ 128
#define BK 64
#define LK (BK + 12)   // 76 halfs: frag-read row bank-step 6 mod 32 -> conflict-free

__global__ __launch_bounds__(256) void attn_mfma_kernel(
    const f16* __restrict__ q, const f16* __restrict__ k,
    const f16* __restrict__ vT, f16* __restrict__ Opart, float* __restrict__ lpart)
{
    __shared__ f16 Ks[2][BK][LK];    // permuted key rows
    __shared__ f16 VsT[2][EE][LK];   // [e][key]

    const int tid = threadIdx.x;
    const int h = blockIdx.y;
    const int n0 = blockIdx.x * BQ;
    const int sp = blockIdx.z;
    const int nsp = gridDim.z;
    const int wave = tid >> 6;
    const int lane = tid & 63;
    const int l16 = lane & 15;
    const int quad = lane >> 4;
    const int m0 = wave * 16;

    const f16* qh = q + (size_t)h * NN * EE;
    const f16* kh = k + (size_t)h * NN * EE;
    const f16* vh = vT + (size_t)h * NN * EE;  // [e][n]

    // Q B-fragments for both strips (loaded once from global)
    f16x8 qf[2][2];
    #pragma unroll
    for (int s = 0; s < 2; ++s) {
        const f16* qb = qh + (size_t)(n0 + s * 64 + m0 + l16) * EE;
        qf[s][0] = *(const f16x8*)(qb + quad * 8);
        qf[s][1] = *(const f16x8*)(qb + 32 + quad * 8);
    }

    float lp[2] = {0.f, 0.f};
    f32x4 O[2][4];
    #pragma unroll
    for (int s = 0; s < 2; ++s)
        #pragma unroll
        for (int t = 0; t < 4; ++t) O[s][t] = (f32x4){0.f, 0.f, 0.f, 0.f};

    const int span = NN / nsp;
    const int k_begin = sp * span;
    const int k_end = k_begin + span;

    const int srow = tid >> 3, sc8 = (tid & 7) * 8;
    const int srow2 = (tid + 256) >> 3, sc82 = ((tid + 256) & 7) * 8;
    // key -> permuted LDS row: bits T,q,u,c -> T,u,q,c (verified r6)
    #define KPERM(kk_) (((kk_) & 0x23) | (((kk_) & 0x04) << 2) | (((kk_) & 0x18) >> 1))
    const int prow1 = KPERM(srow), prow2 = KPERM(srow2);

    // register prefetch of first tile
    f16x8 kr0 = *(const f16x8*)(kh + (size_t)(k_begin + srow) * EE + sc8);
    f16x8 kr1 = *(const f16x8*)(kh + (size_t)(k_begin + srow2) * EE + sc82);
    f16x8 vr0 = *(const f16x8*)(vh + (size_t)srow * NN + k_begin + sc8);
    f16x8 vr1 = *(const f16x8*)(vh + (size_t)srow2 * NN + k_begin + sc82);

    int buf = 0;
    for (int kt = k_begin; kt < k_end; kt += BK) {
        *(f16x8*)(&Ks[buf][prow1][sc8]) = kr0;
        *(f16x8*)(&Ks[buf][prow2][sc82]) = kr1;
        *(f16x8*)(&VsT[buf][srow][sc8]) = vr0;
        *(f16x8*)(&VsT[buf][srow2][sc82]) = vr1;
        __syncthreads();   // single barrier: this buf's writes visible; other buf still being read? no — see dbuf proof

        if (kt + BK < k_end) {   // prefetch next tile (lands in the other buffer next iter)
            kr0 = *(const f16x8*)(kh + (size_t)(kt + BK + srow) * EE + sc8);
            kr1 = *(const f16x8*)(kh + (size_t)(kt + BK + srow2) * EE + sc82);
            vr0 = *(const f16x8*)(vh + (size_t)srow * NN + kt + BK + sc8);
            vr1 = *(const f16x8*)(vh + (size_t)srow2 * NN + kt + BK + sc82);
        }

        // S^T = K.Q^T per key-tile; each K-frag read feeds both q-strips
        f16x8 bf[2][2];
        #pragma unroll
        for (int t = 0; t < 4; ++t) {
            f16x8 a0 = *(const f16x8*)(&Ks[buf][t * 16 + l16][quad * 8]);
            f16x8 a1 = *(const f16x8*)(&Ks[buf][t * 16 + l16][32 + quad * 8]);
            #pragma unroll
            for (int s = 0; s < 2; ++s) {
                f32x4 st = {0.f, 0.f, 0.f, 0.f};
                st = __builtin_amdgcn_mfma_f32_16x16x32_f16(a0, qf[s][0], st, 0, 0, 0);
                st = __builtin_amdgcn_mfma_f32_16x16x32_f16(a1, qf[s][1], st, 0, 0, 0);
                float p0 = hexp2(st[0]);
                float p1 = hexp2(st[1]);
                float p2 = hexp2(st[2]);
                float p3 = hexp2(st[3]);
                lp[s] += (p0 + p1) + (p2 + p3);
                f16x8& b = bf[s][t >> 1];
                const int o = (t & 1) * 4;
                b[o + 0] = (f16)p0; b[o + 1] = (f16)p1;
                b[o + 2] = (f16)p2; b[o + 3] = (f16)p3;
            }
        }

        // O^T += V^T P^T ; each V-frag read feeds both strips
        #pragma unroll
        for (int te = 0; te < 4; ++te) {
            f16x8 v0 = *(const f16x8*)(&VsT[buf][te * 16 + l16][quad * 8]);
            f16x8 v1 = *(const f16x8*)(&VsT[buf][te * 16 + l16][32 + quad * 8]);
            #pragma unroll
            for (int s = 0; s < 2; ++s) {
                O[s][te] = __builtin_amdgcn_mfma_f32_16x16x32_f16(v0, bf[s][0], O[s][te], 0, 0, 0);
                O[s][te] = __builtin_amdgcn_mfma_f32_16x16x32_f16(v1, bf[s][1], O[s][te], 0, 0, 0);
            }
        }
        buf ^= 1;
    }

    // epilogue per strip: normalize by local l, store f16
    #pragma unroll
    for (int s = 0; s < 2; ++s) {
        float l = lp[s];
        l += __shfl_xor(l, 16);
        l += __shfl_xor(l, 32);
        const int row = n0 + s * 64 + m0 + l16;
        if (quad == 0)
            lpart[(size_t)sp * HH * NN + (size_t)h * NN + row] = l;
        const float inv = 1.f / l;
        f16* obase = Opart + ((size_t)sp * NN + row) * DD + h * EE;
        #pragma unroll
        for (int te = 0; te < 4; ++te) {
            f16x4 v = { (f16)(O[s][te][0] * inv), (f16)(O[s][te][1] * inv),
                        (f16)(O[s][te][2] * inv), (f16)(O[s][te][3] * inv) };
            *(f16x4*)(obase + te * 16 + quad * 4) = v;
        }
    }
}

// ---------------- combine: zh = sum_s (l_s/sum l) * Ohat_s, f16 out ----------------
__global__ __launch_bounds__(256) void attn_combine_kernel(
    const f16* __restrict__ Opart, const float* __restrict__ lpart, f16* __restrict__ zh, int nsp)
{
    const size_t idx = ((size_t)blockIdx.x * 256 + threadIdx.x) * 8;
    const int n = (int)(idx >> 9);
    const int h = (int)((idx & 511) >> 6);
    float lw[8];
    float lsum = 0.f;
    for (int s = 0; s < nsp; ++s) {
        lw[s] = lpart[(size_t)s * HH * NN + (size_t)h * NN + n];
        lsum += lw[s];
    }
    const float inv = 1.f / lsum;
    float acc[8];
    #pragma unroll
    for (int i = 0; i < 8; ++i) acc[i] = 0.f;
    for (int s = 0; s < nsp; ++s) {
        f16x8 o = *(const f16x8*)(Opart + (size_t)s * NN * DD + idx);
        const float w = lw[s] * inv;
        #pragma unroll
        for (int i = 0; i < 8; ++i) acc[i] += w * (float)o[i];
    }
    f16x8 z;
    #pragma unroll
    for (int i = 0; i < 8; ++i) z[i] = (f16)acc[i];
    *(f16x8*)(zh + idx) = z;
}

// ---------------- GEMM via MFMA + bias/f16-residual epilogue, f16 out, double-buffered ----------------
__global__ __launch_bounds__(256) void gemm_mfma_kernel(
    const f16* __restrict__ A, const f16* __restrict__ BT,
    const float* __restrict__ bias, const f16* __restrict__ resid16,
    f16* __restrict__ out)
{
    __shared__ f16 As[2][64][72];
    __shared__ f16 Bs[2][64][72];
    const int tid = threadIdx.x;
    const int n0 = blockIdx.x * 64;
    const int j0 = blockIdx.y * 64;
    const f16* Arow = A + (size_t)n0 * DD;
    const f16* Brow = BT + (size_t)j0 * DD;

    const int lane = tid & 63, wave = tid >> 6;
    const int l16 = lane & 15, quad = lane >> 4;
    const int m0 = wave * 16;

    const int r1 = tid >> 3, c1 = (tid & 7) * 8;
    const int r2 = (tid + 256) >> 3, c2 = ((tid + 256) & 7) * 8;

    f32x4 acc[4];
    #pragma unroll
    for (int t = 0; t < 4; ++t) acc[t] = (f32x4){0.f, 0.f, 0.f, 0.f};

    f16x8 a1 = *(const f16x8*)(Arow + (size_t)r1 * DD + c1);
    f16x8 a2 = *(const f16x8*)(Arow + (size_t)r2 * DD + c2);
    f16x8 b1 = *(const f16x8*)(Brow + (size_t)r1 * DD + c1);
    f16x8 b2 = *(const f16x8*)(Brow + (size_t)r2 * DD + c2);

    int buf = 0;
    for (int kt = 0; kt < DD; kt += 64) {
        *(f16x8*)(&As[buf][r1][c1]) = a1;
        *(f16x8*)(&As[buf][r2][c2]) = a2;
        *(f16x8*)(&Bs[buf][r1][c1]) = b1;
        *(f16x8*)(&Bs[buf][r2][c2]) = b2;
        __syncthreads();
        if (kt + 64 < DD) {
            a1 = *(const f16x8*)(Arow + (size_t)r1 * DD + kt + 64 + c1);
            a2 = *(const f16x8*)(Arow + (size_t)r2 * DD + kt + 64 + c2);
            b1 = *(const f16x8*)(Brow + (size_t)r1 * DD + kt + 64 + c1);
            b2 = *(const f16x8*)(Brow + (size_t)r2 * DD + kt + 64 + c2);
        }
        #pragma unroll
        for (int kk = 0; kk < 64; kk += 32) {
            f16x8 a = *(const f16x8*)(&As[buf][m0 + l16][kk + quad * 8]);
            #pragma unroll
            for (int t = 0; t < 4; ++t) {
                f16x8 b = *(const f16x8*)(&Bs[buf][t * 16 + l16][kk + quad * 8]);
                acc[t] = __builtin_amdgcn_mfma_f32_16x16x32_f16(a, b, acc[t], 0, 0, 0);
            }
        }
        buf ^= 1;
    }

    #pragma unroll
    for (int r = 0; r < 4; ++r) {
        int row = n0 + m0 + quad * 4 + r;
        #pragma unroll
        for (int t = 0; t < 4; ++t) {
            int col = j0 + t * 16 + l16;
            float v = acc[t][r];
            if (bias)    v += bias[col];
            if (resid16) v += (float)resid16[(size_t)row * DD + col];
            out[(size_t)row * DD + col] = (f16)v;
        }
    }
}

// ---------------- row LayerNorm: y f16 [N][512] -> f16 and/or fp32 out ----------------
__global__ __launch_bounds__(256) void ln_kernel(
    const f16* __restrict__ y, const float* __restrict__ g, const float* __restrict__ b,
    f16* __restrict__ oh, float* __restrict__ of)
{
    const int lane = threadIdx.x & 63, wave = threadIdx.x >> 6;
    const int row = blockIdx.x * 4 + wave;
    f16x8 v = *(const f16x8*)(y + (size_t)row * DD + lane * 8);
    float vf[8];
    float s = 0.f, q = 0.f;
    #pragma unroll
    for (int i = 0; i < 8; ++i) {
        vf[i] = (float)v[i];
        s += vf[i];
        q += vf[i] * vf[i];
    }
    #pragma unroll
    for (int o = 1; o < 64; o <<= 1) { s += __shfl_xor(s, o); q += __shfl_xor(q, o); }
    float mean = s * (1.f / DD);
    float var = q * (1.f / DD) - mean * mean;
    float inv = rsqrtf(var + 1e-5f);

    f32x4 g0 = *(const f32x4*)(g + lane * 8);
    f32x4 g1 = *(const f32x4*)(g + lane * 8 + 4);
    f32x4 b0 = *(const f32x4*)(b + lane * 8);
    f32x4 b1 = *(const f32x4*)(b + lane * 8 + 4);
    float o8[8];
    #pragma unroll
    for (int i = 0; i < 4; ++i) {
        o8[i]     = (vf[i] - mean) * inv * g0[i] + b0[i];
        o8[i + 4] = (vf[i + 4] - mean) * inv * g1[i] + b1[i];
    }
    if (oh) {
        f16x8 hv;
        #pragma unroll
        for (int i = 0; i < 8; ++i) hv[i] = (f16)o8[i];
        *(f16x8*)(oh + (size_t)row * DD + lane * 8) = hv;
    }
    if (of) {
        f32x4 f0 = { o8[0], o8[1], o8[2], o8[3] };
        f32x4 f1 = { o8[4], o8[5], o8[6], o8[7] };
        *(f32x4*)(of + (size_t)row * DD + lane * 8) = f0;
        *(f32x4*)(of + (size_t)row * DD + lane * 8 + 4) = f1;
    }
}

extern "C" void kernel_launch(void* const* d_in, const int* in_sizes, int n_in,
                              void* d_out, int out_size, void* d_ws, size_t ws_size,
                              hipStream_t stream) {
    const float* x     = (const float*)d_in[0];
    const float* wq    = (const float*)d_in[1];
    const float* wk    = (const float*)d_in[2];
    const float* wv    = (const float*)d_in[3];
    const float* w_mh  = (const float*)d_in[4];
    const float* ln1_g = (const float*)d_in[5];
    const float* ln1_b = (const float*)d_in[6];
    const float* ffn_w = (const float*)d_in[7];
    const float* ffn_b = (const float*)d_in[8];
    const float* ln2_g = (const float*)d_in[9];
    const float* ln2_b = (const float*)d_in[10];
    float* out = (float*)d_out;

    // persistent f16 pool (xh now persistent: it's gemm1's residual)
    const size_t poolBytes = ((size_t)3 * HH * EE * DD + 2 * (size_t)DD * DD
                            + 3 * (size_t)HH * NN * EE + 3 * (size_t)NN * DD) * 2;
    // K-split: SP=4 (r8/r9 showed SP=4 == SP=8 for attn; SP=4 halves combine traffic)
    int SP = 2;
    {
        size_t need4 = (size_t)4 * NN * DD * 2 + (size_t)4 * HH * NN * 4 + poolBytes + 4096;
        if (ws_size >= need4) SP = 4;
    }

    // region A (aliased): Opart+lpart (attn..combine) / y16 (post-combine)
    char* base = (char*)d_ws;
    f16* Opart = (f16*)base;                                        // SP*NN*DD f16
    float* lpart = (float*)(base + (size_t)SP * NN * DD * 2);       // SP*HH*NN f32
    f16* y16  = (f16*)base;                                         // alias (post-combine)
    size_t regionA = (size_t)SP * NN * DD * 2 + (size_t)SP * HH * NN * 4;
    regionA = (regionA + 255) & ~(size_t)255;
    f16* p = (f16*)(base + regionA);
    f16* wqkvT  = p; p += (size_t)3 * HH * EE * DD;           // [sel][h][e][d]
    f16* wmhT   = p; p += (size_t)DD * DD;                    // [j][k]
    f16* ffnT   = p; p += (size_t)DD * DD;                    // [j][k]
    f16* qh     = p; p += (size_t)HH * NN * EE;               // [h][n][e], scale baked
    f16* kh     = p; p += (size_t)HH * NN * EE;               // [h][n][e]
    f16* vTh    = p; p += (size_t)HH * NN * EE;               // [h][e][n]
    f16* zh     = p; p += (size_t)NN * DD;                    // [n][h*e]
    f16* nzh    = p; p += (size_t)NN * DD;                    // LN1 out
    f16* xh     = p; p += (size_t)NN * DD;                    // persistent: gemm1 residual

    // prep (single launch)
    prep_kernel<<<dim3(256, 6), 256, 0, stream>>>(x, ffn_w, wq, wk, wv, w_mh,
                                                  xh, ffnT, wqkvT, wmhT);

    // main chain
    qkv_mfma_kernel<<<dim3(NN / 64, 24), 256, 0, stream>>>(xh, wqkvT, qh, kh, vTh);
    attn_mfma_kernel<<<dim3(NN / BQ, HH, SP), 256, 0, stream>>>(qh, kh, vTh, Opart, lpart);
    attn_combine_kernel<<<dim3(NN * DD / 2048), 256, 0, stream>>>(Opart, lpart, zh, SP);
    gemm_mfma_kernel<<<dim3(NN / 64, DD / 64), 256, 0, stream>>>(zh, wmhT, nullptr, xh, y16);
    ln_kernel<<<dim3(NN / 4), 256, 0, stream>>>(y16, ln1_g, ln1_b, nzh, nullptr);
    gemm_mfma_kernel<<<dim3(NN / 64, DD / 64), 256, 0, stream>>>(nzh, ffnT, ffn_b, nzh, y16);
    ln_kernel<<<dim3(NN / 4), 256, 0, stream>>>(y16, ln2_g, ln2_b, nullptr, out);
}